// Round 11
// baseline (106.666 us; speedup 1.0000x reference)
//
#include <hip/hip_runtime.h>
#include <stdint.h>

// Problem constants (from the reference)
constexpr int Tdim = 4096;   // time / input width
constexpr int Ndim = 4096;   // neurons
constexpr int Bdim = 1024;   // batch
constexpr int NB   = 16;     // address bits
constexpr int WPN  = 2115;   // words per neuron = ceil(65536 / 31)

// ---------------------------------------------------------------------------
// Per-wave layout probe: int64-on-device arrays (values < 2^31) have zero
// high halves at every odd int32 slot. 64 probes via ballot; false positive
// <= 2^-64. Returns the int32-index multiplier (2 = int64, 1 = int32).
// ---------------------------------------------------------------------------
__device__ __forceinline__ int probe_stride(const int* __restrict__ p) {
    const int l = threadIdx.x & 63;
    return (__ballot(p[2 * l + 1] == 0) == ~0ull) ? 2 : 1;
}

// ---------------------------------------------------------------------------
// Kernel 1: pack x (B x T of 0/1) into bit-planes:
//   xT[bg * T + t] = uint32 whose bit bl = x[(bg*32 + bl) * T + t]
// int64 layout: uint2 loads (8 B/lane coalesced, half the instructions of
// 4B-at-stride-8). Same HBM line traffic (32 MB), fewer issue slots.
// ---------------------------------------------------------------------------
__global__ __launch_bounds__(256) void pack_kernel(const int* __restrict__ x,
                                                   uint32_t* __restrict__ xT) {
    const int sx = probe_stride(x);
    const int t  = blockIdx.x * 256 + threadIdx.x;
    const int bg = blockIdx.y;
    uint32_t w = 0;
    if (sx == 2) {
        const uint2* x2 = (const uint2*)x;
#pragma unroll
        for (int bl = 0; bl < 32; ++bl)
            w |= (x2[(size_t)(bg * 32 + bl) * Tdim + t].x & 1u) << bl;
    } else {
#pragma unroll
        for (int bl = 0; bl < 32; ++bl)
            w |= (uint32_t)(x[(size_t)(bg * 32 + bl) * Tdim + t] & 1) << bl;
    }
    xT[(size_t)bg * Tdim + t] = w;
}

// ---------------------------------------------------------------------------
// Kernel 2 v6 (stream + packed-emit, 1 neuron/block): block = 256 thr =
// 1 neuron x ALL 1024 batches; grid = N = 4096. LDS 10.8 KB -> 8 blocks/CU
// (thread-limited, exact), 2 scheduling passes, small barrier quanta ->
// block-level TLP hides the stream latency (r10 post-mortem lever).
//
// Phase A1: stream row n (2115 words) -> rowbuf, coalesced (L3-resident
//           table after harness restore; FETCH stays ~23 MB).
// Phase A2: gather 32x16 conn-bit matrix from L2-resident xT -> bits.
// Phase B : per pass: 4 x ds_read_b128 -> 16-bit addr -> random LDS read
//           rowbuf[wi] -> 2-bit val, ballot-packed (r9 lesson: no scattered
//           8B stores; packed emit keeps WRITE_SIZE ~1 MB).
// Phase C : 256 B contiguous packed emit -> pmask.
// ---------------------------------------------------------------------------
__global__ __launch_bounds__(256) void row_kernel(const uint32_t* __restrict__ xT,
                                                  const int* __restrict__ conn,
                                                  const int* __restrict__ mem,
                                                  uint64_t* __restrict__ pmask) {
    const int sc = probe_stride(conn);
    const int sm = probe_stride(mem);

    const int n   = blockIdx.x;
    const int tid = threadIdx.x;

    __shared__ uint32_t rowbuf[WPN];           // 8.46 KB compacted row
    __shared__ uint4    bits4[32 * 4];         // [bg][j/4] 2 KB (16B aligned)
    __shared__ uint64_t omask[32];             // [pass*2+plane] 256 B
    uint32_t* bits = (uint32_t*)bits4;

    // Phase A1: stream 2115 table words, coalesced (sequential lines)
    const size_t base = (size_t)n * WPN;
    if (sm == 2) {                             // int64 layout: uint2, keep .x
        const uint2* m2 = (const uint2*)mem;
#pragma unroll
        for (int k = 0; k < 9; ++k) {
            const int idx = k * 256 + tid;
            if (idx < WPN) rowbuf[idx] = m2[base + idx].x;
        }
    } else {                                   // int32 layout
        const uint32_t* m1 = (const uint32_t*)mem;
#pragma unroll
        for (int k = 0; k < 9; ++k) {
            const int idx = k * 256 + tid;
            if (idx < WPN) rowbuf[idx] = m1[base + idx];
        }
    }

    // Phase A2: conn-bit matrix gather (xT is 512 KB, L2-resident per XCD)
#pragma unroll
    for (int k = 0; k < 2; ++k) {
        const int idx = k * 256 + tid;         // [0,512)
        const int bg  = idx >> 4;
        const int j   = idx & 15;
        const int c   = conn[(n * NB + j) * sc];
        bits[idx] = xT[(size_t)bg * Tdim + c];
    }
    __syncthreads();                           // single latency exposure

    // Phase B: 1024 lookups, all from LDS; 4 waves x 4 passes
    const int w   = tid >> 6;                  // wave 0..3
    const int l   = tid & 63;
    const int bit = l & 31;
    const int hi  = l >> 5;
#pragma unroll
    for (int it = 0; it < 4; ++it) {
        const int p  = w * 4 + it;             // pass: batches p*64 .. p*64+63
        const int bg = p * 2 + hi;             // b = bg*32 + bit = p*64 + l
        const uint4* bp4 = &bits4[bg * 4];
        uint32_t wv[16];
#pragma unroll
        for (int q = 0; q < 4; ++q) {          // 4 x ds_read_b128
            const uint4 v4 = bp4[q];
            wv[q * 4 + 0] = v4.x; wv[q * 4 + 1] = v4.y;
            wv[q * 4 + 2] = v4.z; wv[q * 4 + 3] = v4.w;
        }
        uint32_t addr = 0;
#pragma unroll
        for (int j = 0; j < 16; ++j)           // conn[0] = MSB (ref weights)
            addr = (addr << 1) | ((wv[j] >> bit) & 1u);
        const uint32_t wi = addr / 31u;        // magic-mul
        const uint32_t sh = (addr - wi * 31u) * 2u;   // 0..60
        // uint64 promote: sh>=32 -> 0, matching the int64 reference
        const uint32_t v = (uint32_t)(((uint64_t)rowbuf[wi] >> sh) & 3ull);
        const uint64_t b0 = __ballot((v & 1u) != 0u);
        const uint64_t b1 = __ballot((v & 2u) != 0u);
        if (l == 0) {
            omask[p * 2 + 0] = b0;
            omask[p * 2 + 1] = b1;
        }
    }
    __syncthreads();

    // Phase C: 32 x uint64 = 256 B contiguous packed emit
    if (tid < 32) pmask[(size_t)n * 32 + tid] = omask[tid];
}

// ---------------------------------------------------------------------------
// Kernel 3 (unpack): block = 16 neurons x 1024 batches; grid = N/16 = 256.
// Reads 4 KB of packed masks, writes 64 KB of out as FULL 64-B lines
// (wave = 4 batches x 16 neurons). Pure streaming.
// ---------------------------------------------------------------------------
__global__ __launch_bounds__(256) void unpack_kernel(const uint64_t* __restrict__ pmask,
                                                     int* __restrict__ out) {
    const int n0  = blockIdx.x * 16;
    const int tid = threadIdx.x;

    __shared__ uint64_t m[16 * 32];            // [n_l][p*2+plane] 4 KB
#pragma unroll
    for (int k = 0; k < 2; ++k) {
        const int idx = k * 256 + tid;
        m[idx] = pmask[(size_t)n0 * 32 + idx];
    }
    __syncthreads();

    const int nl = tid & 15;                   // local neuron column
    const int b0 = tid >> 4;                   // 0..15
#pragma unroll
    for (int q = 0; q < 64; ++q) {
        const int b = q * 16 + b0;             // [0,1024)
        const int p = b >> 6;
        const int s = b & 63;
        const uint64_t m0 = m[nl * 32 + p * 2 + 0];
        const uint64_t m1 = m[nl * 32 + p * 2 + 1];
        const int v = (int)((m0 >> s) & 1ull) | ((int)((m1 >> s) & 1ull) << 1);
        out[(size_t)b * Ndim + n0 + nl] = v;
    }
}

// ---------------------------------------------------------------------------
// Fallback (only if ws_size too small): direct per-(b,n) gather. Correct, slower.
// ---------------------------------------------------------------------------
__global__ __launch_bounds__(256) void direct_kernel(const int* __restrict__ x,
                                                     const int* __restrict__ conn,
                                                     const int* __restrict__ mem,
                                                     int* __restrict__ out) {
    const int sx = probe_stride(x);
    const int sc = probe_stride(conn);
    const int sm = probe_stride(mem);
    const int n  = blockIdx.x * 256 + threadIdx.x;   // lane = n -> coalesced store
    const int b  = blockIdx.y;
    const int* cp = conn + (size_t)n * NB * sc;
    const int* xr = x + (size_t)b * Tdim * sx;
    uint32_t addr = 0;
#pragma unroll
    for (int j = 0; j < 16; ++j)
        addr = (addr << 1) | (uint32_t)(xr[(size_t)cp[j * sc] * sx] & 1);
    const uint32_t wi = addr / 31u;
    const uint32_t sh = (addr - wi * 31u) * 2u;
    const uint64_t wd = (uint32_t)mem[((size_t)n * WPN + wi) * sm];
    out[(size_t)b * Ndim + n] = (int)((wd >> sh) & 3u);
}

// ---------------------------------------------------------------------------
extern "C" void kernel_launch(void* const* d_in, const int* in_sizes, int n_in,
                              void* d_out, int out_size, void* d_ws, size_t ws_size,
                              hipStream_t stream) {
    const int* x    = (const int*)d_in[0];       // (B, T) 0/1
    const int* conn = (const int*)d_in[1];       // (N, 16) indices < T
    const int* mem  = (const int*)d_in[2];       // (N, WPN), values < 2^31
    int*       out  = (int*)d_out;               // (B, N), read back as np.int32
    uint32_t*  xT   = (uint32_t*)d_ws;           // bit-planes, 512 KB
    uint64_t*  pmask = (uint64_t*)((char*)d_ws + (size_t)(Bdim / 32) * Tdim * 4);

    const size_t need = (size_t)(Bdim / 32) * Tdim * 4 + (size_t)Ndim * 32 * 8;
    if (ws_size >= need) {
        dim3 g1(Tdim / 256, Bdim / 32);          // 16 x 32 = 512 blocks
        pack_kernel<<<g1, 256, 0, stream>>>(x, xT);
        row_kernel<<<Ndim, 256, 0, stream>>>(xT, conn, mem, pmask);
        unpack_kernel<<<Ndim / 16, 256, 0, stream>>>(pmask, out);
    } else {
        dim3 g3(Ndim / 256, Bdim);               // 16 x 1024 blocks
        direct_kernel<<<g3, 256, 0, stream>>>(x, conn, mem, out);
    }
}

// Round 12
// 104.475 us; speedup vs baseline: 1.0210x; 1.0210x over previous
//
#include <hip/hip_runtime.h>
#include <stdint.h>

// Problem constants (from the reference)
constexpr int Tdim = 4096;   // time / input width
constexpr int Ndim = 4096;   // neurons
constexpr int Bdim = 1024;   // batch
constexpr int NB   = 16;     // address bits
constexpr int WPN  = 2115;   // words per neuron = ceil(65536 / 31)

// ---------------------------------------------------------------------------
// Per-wave layout probe: int64-on-device arrays (values < 2^31) have zero
// high halves at every odd int32 slot. 64 probes via ballot; false positive
// <= 2^-64. Returns the int32-index multiplier (2 = int64, 1 = int32).
// ---------------------------------------------------------------------------
__device__ __forceinline__ int probe_stride(const int* __restrict__ p) {
    const int l = threadIdx.x & 63;
    return (__ballot(p[2 * l + 1] == 0) == ~0ull) ? 2 : 1;
}

// ---------------------------------------------------------------------------
// Kernel 1: pack x into T-MAJOR bit-planes:
//   xT2[t * 32 + bg] = uint32 whose bit bl = x[(bg*32 + bl) * T + t]
// r11 post-mortem: bg-major layout made row_kernel's A2 phase read 512
// distinct 64-B lines per block (134 MB of L2 traffic chip-wide). t-major
// puts a conn-column's 32 words in 128 contiguous bytes -> 32 lines/block.
// Pack writes are scattered 4-B (L2-absorbed, 512 KB total); kernel-boundary
// flush publishes them to L3, so cross-XCD visibility is guaranteed.
// ---------------------------------------------------------------------------
__global__ __launch_bounds__(256) void pack_kernel(const int* __restrict__ x,
                                                   uint32_t* __restrict__ xT2) {
    const int sx = probe_stride(x);
    const int t  = blockIdx.x * 256 + threadIdx.x;
    const int bg = blockIdx.y;
    uint32_t w = 0;
    if (sx == 2) {
        const uint2* x2 = (const uint2*)x;
#pragma unroll
        for (int bl = 0; bl < 32; ++bl)
            w |= (x2[(size_t)(bg * 32 + bl) * Tdim + t].x & 1u) << bl;
    } else {
#pragma unroll
        for (int bl = 0; bl < 32; ++bl)
            w |= (uint32_t)(x[(size_t)(bg * 32 + bl) * Tdim + t] & 1) << bl;
    }
    xT2[(size_t)t * 32 + bg] = w;
}

// ---------------------------------------------------------------------------
// Kernel 2 v7 (stream + packed-emit + dense A2): block = 256 thr = 1 neuron
// x ALL 1024 batches; grid = N = 4096.
//
// Phase A1: stream row n (2115 words) -> rowbuf, coalesced uint2.
// Phase A2: 16 conn-columns as dense 128-B segments (t-major xT2) ->
//           staging bits_t (padded, coalesced) -> in-LDS transpose -> bits4.
// Phase B : per pass: 4 x ds_read_b128 -> 16-bit addr -> random LDS read
//           rowbuf[wi] -> 2-bit val, ballot-packed.
// Phase C : 256 B contiguous packed emit -> pmask (r9 lesson: no scattered
//           8-B stores to out; they cost 66 MB of partial-line HBM writes).
// ---------------------------------------------------------------------------
__global__ __launch_bounds__(256) void row_kernel(const uint32_t* __restrict__ xT2,
                                                  const int* __restrict__ conn,
                                                  const int* __restrict__ mem,
                                                  uint64_t* __restrict__ pmask) {
    const int sc = probe_stride(conn);
    const int sm = probe_stride(mem);

    const int n   = blockIdx.x;
    const int tid = threadIdx.x;

    __shared__ uint32_t rowbuf[WPN];           // 8.46 KB compacted row
    __shared__ uint32_t bits_t[16 * 33];       // [j][bg] staging, pad 32->33
    __shared__ uint4    bits4[32 * 4];         // [bg][j/4] 2 KB (16B aligned)
    __shared__ uint64_t omask[32];             // [pass*2+plane] 256 B
    uint32_t* bits = (uint32_t*)bits4;

    // Phase A1: stream 2115 table words, coalesced (sequential lines)
    const size_t base = (size_t)n * WPN;
    if (sm == 2) {                             // int64 layout: uint2, keep .x
        const uint2* m2 = (const uint2*)mem;
#pragma unroll
        for (int k = 0; k < 9; ++k) {
            const int idx = k * 256 + tid;
            if (idx < WPN) rowbuf[idx] = m2[base + idx].x;
        }
    } else {                                   // int32 layout
        const uint32_t* m1 = (const uint32_t*)mem;
#pragma unroll
        for (int k = 0; k < 9; ++k) {
            const int idx = k * 256 + tid;
            if (idx < WPN) rowbuf[idx] = m1[base + idx];
        }
    }

    // Phase A2: 512 words as 16 dense 128-B segments (2 coalesced iters)
#pragma unroll
    for (int k = 0; k < 2; ++k) {
        const int idx = k * 256 + tid;         // [0,512)
        const int j   = idx >> 5;              // conn column 0..15
        const int bg  = idx & 31;
        const int c   = conn[(n * NB + j) * sc];      // half-wave broadcast
        bits_t[j * 33 + bg] = xT2[(size_t)c * 32 + bg];  // dense 128-B segment
    }
    __syncthreads();
    // in-LDS transpose: bits_t[j][bg] -> bits[bg*16 + j] (b128-friendly)
#pragma unroll
    for (int k = 0; k < 2; ++k) {
        const int idx = k * 256 + tid;         // [0,512)
        const int j   = idx & 15;
        const int bg  = idx >> 4;
        bits[bg * 16 + j] = bits_t[j * 33 + bg];
    }
    __syncthreads();

    // Phase B: 1024 lookups, all from LDS; 4 waves x 4 passes
    const int w   = tid >> 6;                  // wave 0..3
    const int l   = tid & 63;
    const int bit = l & 31;
    const int hi  = l >> 5;
#pragma unroll
    for (int it = 0; it < 4; ++it) {
        const int p  = w * 4 + it;             // pass: batches p*64 .. p*64+63
        const int bg = p * 2 + hi;             // b = bg*32 + bit = p*64 + l
        const uint4* bp4 = &bits4[bg * 4];
        uint32_t wv[16];
#pragma unroll
        for (int q = 0; q < 4; ++q) {          // 4 x ds_read_b128 (broadcast)
            const uint4 v4 = bp4[q];
            wv[q * 4 + 0] = v4.x; wv[q * 4 + 1] = v4.y;
            wv[q * 4 + 2] = v4.z; wv[q * 4 + 3] = v4.w;
        }
        uint32_t addr = 0;
#pragma unroll
        for (int j = 0; j < 16; ++j)           // conn[0] = MSB (ref weights)
            addr = (addr << 1) | ((wv[j] >> bit) & 1u);
        const uint32_t wi = addr / 31u;        // magic-mul
        const uint32_t sh = (addr - wi * 31u) * 2u;   // 0..60
        // uint64 promote: sh>=32 -> 0, matching the int64 reference
        const uint32_t v = (uint32_t)(((uint64_t)rowbuf[wi] >> sh) & 3ull);
        const uint64_t b0 = __ballot((v & 1u) != 0u);
        const uint64_t b1 = __ballot((v & 2u) != 0u);
        if (l == 0) {
            omask[p * 2 + 0] = b0;
            omask[p * 2 + 1] = b1;
        }
    }
    __syncthreads();

    // Phase C: 32 x uint64 = 256 B contiguous packed emit
    if (tid < 32) pmask[(size_t)n * 32 + tid] = omask[tid];
}

// ---------------------------------------------------------------------------
// Kernel 3 (unpack): block = 16 neurons x 1024 batches; grid = N/16 = 256.
// Reads 4 KB of packed masks, writes 64 KB of out as FULL 64-B lines.
// ---------------------------------------------------------------------------
__global__ __launch_bounds__(256) void unpack_kernel(const uint64_t* __restrict__ pmask,
                                                     int* __restrict__ out) {
    const int n0  = blockIdx.x * 16;
    const int tid = threadIdx.x;

    __shared__ uint64_t m[16 * 32];            // [n_l][p*2+plane] 4 KB
#pragma unroll
    for (int k = 0; k < 2; ++k) {
        const int idx = k * 256 + tid;
        m[idx] = pmask[(size_t)n0 * 32 + idx];
    }
    __syncthreads();

    const int nl = tid & 15;                   // local neuron column
    const int b0 = tid >> 4;                   // 0..15
#pragma unroll
    for (int q = 0; q < 64; ++q) {
        const int b = q * 16 + b0;             // [0,1024)
        const int p = b >> 6;
        const int s = b & 63;
        const uint64_t m0 = m[nl * 32 + p * 2 + 0];
        const uint64_t m1 = m[nl * 32 + p * 2 + 1];
        const int v = (int)((m0 >> s) & 1ull) | ((int)((m1 >> s) & 1ull) << 1);
        out[(size_t)b * Ndim + n0 + nl] = v;
    }
}

// ---------------------------------------------------------------------------
// Fallback (only if ws_size too small): direct per-(b,n) gather. Correct, slower.
// ---------------------------------------------------------------------------
__global__ __launch_bounds__(256) void direct_kernel(const int* __restrict__ x,
                                                     const int* __restrict__ conn,
                                                     const int* __restrict__ mem,
                                                     int* __restrict__ out) {
    const int sx = probe_stride(x);
    const int sc = probe_stride(conn);
    const int sm = probe_stride(mem);
    const int n  = blockIdx.x * 256 + threadIdx.x;   // lane = n -> coalesced store
    const int b  = blockIdx.y;
    const int* cp = conn + (size_t)n * NB * sc;
    const int* xr = x + (size_t)b * Tdim * sx;
    uint32_t addr = 0;
#pragma unroll
    for (int j = 0; j < 16; ++j)
        addr = (addr << 1) | (uint32_t)(xr[(size_t)cp[j * sc] * sx] & 1);
    const uint32_t wi = addr / 31u;
    const uint32_t sh = (addr - wi * 31u) * 2u;
    const uint64_t wd = (uint32_t)mem[((size_t)n * WPN + wi) * sm];
    out[(size_t)b * Ndim + n] = (int)((wd >> sh) & 3u);
}

// ---------------------------------------------------------------------------
extern "C" void kernel_launch(void* const* d_in, const int* in_sizes, int n_in,
                              void* d_out, int out_size, void* d_ws, size_t ws_size,
                              hipStream_t stream) {
    const int* x    = (const int*)d_in[0];       // (B, T) 0/1
    const int* conn = (const int*)d_in[1];       // (N, 16) indices < T
    const int* mem  = (const int*)d_in[2];       // (N, WPN), values < 2^31
    int*       out  = (int*)d_out;               // (B, N), read back as np.int32
    uint32_t*  xT2  = (uint32_t*)d_ws;           // t-major bit-planes, 512 KB
    uint64_t*  pmask = (uint64_t*)((char*)d_ws + (size_t)Tdim * 32 * 4);

    const size_t need = (size_t)Tdim * 32 * 4 + (size_t)Ndim * 32 * 8;
    if (ws_size >= need) {
        dim3 g1(Tdim / 256, Bdim / 32);          // 16 x 32 = 512 blocks
        pack_kernel<<<g1, 256, 0, stream>>>(x, xT2);
        row_kernel<<<Ndim, 256, 0, stream>>>(xT2, conn, mem, pmask);
        unpack_kernel<<<Ndim / 16, 256, 0, stream>>>(pmask, out);
    } else {
        dim3 g3(Ndim / 256, Bdim);               // 16 x 1024 blocks
        direct_kernel<<<g3, 256, 0, stream>>>(x, conn, mem, out);
    }
}